// Round 20
// baseline (179.868 us; speedup 1.0000x reference)
//
#include <hip/hip_runtime.h>

#define KCLS 19
#define CCH 64
#define HW (512*512)
#define NPIX (4*HW)          // 1,048,576 pixels

// K1 geometry: channel-major contiguous
#define CHUNK 16384          // pixels per chunk (16 chunks per image)
#define NCHUNK (NPIX/CHUNK)  // 64
#define NCGRP 16             // channel groups of 4
#define CPG 4

// ws float offsets (stats area)
#define WS_COUNTS  0      // 19
#define WS_SUMS    32     // [k*64+c], 1216
#define WS_VARSUM  1280   // 19
#define WS_NFLOATS 2576
#define WS_U8_BYTE_OFF  16384                      // packed u8 labels, 1 MB
#define WS_FP8_BYTE_OFF (16384 + 1048576)          // fp8 copy of pred (plane layout), 64 MB

typedef float f32x2 __attribute__((ext_vector_type(2)));

__device__ __forceinline__ void ldsAdd(float* p, float v) { unsafeAtomicAdd(p, v); }

// ---------------- K0: zero stats + pack labels to u8 ----------------
__global__ __launch_bounds__(256) void k0_prep(const int* __restrict__ tgt,
                                               float* __restrict__ ws,
                                               unsigned* __restrict__ u8buf) {
    const int j = blockIdx.x * 256 + threadIdx.x;
    if (blockIdx.x == 0) {
        for (int i = threadIdx.x; i < WS_NFLOATS; i += 256) ws[i] = 0.0f;
    }
    const int4* tg4 = (const int4*)tgt;
    unsigned pk[4];
    #pragma unroll
    for (int q = 0; q < 4; ++q) {
        int4 L = tg4[j * 4 + q];
        pk[q] = (unsigned)(L.x & 0xFF) | ((unsigned)(L.y & 0xFF) << 8) |
                ((unsigned)(L.z & 0xFF) << 16) | ((unsigned)(L.w & 0xFF) << 24);
    }
    uint4 o; o.x = pk[0]; o.y = pk[1]; o.z = pk[2]; o.w = pk[3];
    ((uint4*)u8buf)[j] = o;
}

// ---------------- K1: counts + sums + fp8 copy; BARRIER-FREE channel loop ----------------
// grid (64 chunks, 16 cgroups), block 256 (4 waves).
// Flush is wave-local (lane k sums its wave's 64 rows) -> no __syncthreads in the
// channel loop -> no vmcnt(0) store-drain stalls. One barrier total (label staging).
__global__ __launch_bounds__(256) void k1_sums(const float* __restrict__ pred,
                                               const unsigned* __restrict__ u8buf,
                                               float* __restrict__ ws,
                                               unsigned* __restrict__ fp8buf) {
    const int t = threadIdx.x;
    const int l = t & 63;
    const int w = t >> 6;
    const int chunk = blockIdx.x;        // 64
    const int cg = blockIdx.y;           // 16
    const int n = chunk >> 4;
    const int choff = (chunk & 15) * CHUNK;

    __shared__ unsigned labw[CHUNK / 4];      // 16 KB packed u8 labels
    __shared__ float bins[256 * 21];          // 21.5 KB thread-private rows
    __shared__ float cnt[16 * 21];            // 1.3 KB replica count hist

    float* br = &bins[t * 21];
    #pragma unroll
    for (int k = 0; k < KCLS; ++k) br[k] = 0.0f;
    for (int i = t; i < 16 * 21; i += 256) cnt[i] = 0.0f;
    __syncthreads();

    // stage labels + count histogram (16 replicas)
    {
        const uint4* g4 = (const uint4*)(u8buf + chunk * (CHUNK / 4));
        #pragma unroll
        for (int q = 0; q < 4; ++q) {
            uint4 v = g4[t + q * 256];
            ((uint4*)labw)[t + q * 256] = v;
        }
        unsigned cw = ((const unsigned*)(u8buf + chunk * (CHUNK / 4)))[cg * 256 + t];
        float* cr = &cnt[(t & 15) * 21];
        ldsAdd(&cr[cw & 31], 1.0f);
        ldsAdd(&cr[(cw >> 8) & 31], 1.0f);
        ldsAdd(&cr[(cw >> 16) & 31], 1.0f);
        ldsAdd(&cr[(cw >> 24) & 31], 1.0f);
    }
    __syncthreads();      // the ONLY block barrier (before any NT store)

    // flush counts now (cnt complete, cheap drain)
    if (t < KCLS) {
        float s = 0.0f;
        #pragma unroll
        for (int r = 0; r < 16; ++r) s += cnt[r * 21 + t];
        unsafeAtomicAdd(&ws[WS_COUNTS + t], s);
    }

    for (int c4 = 0; c4 < CPG; ++c4) {
        const int c = cg * CPG + c4;
        const size_t plane = (size_t)(n * CCH + c) * HW + choff;
        const float4* src = (const float4*)(pred + plane) + w * 1024;
        unsigned* dst8 = fp8buf + (plane >> 2) + w * 1024;
        const unsigned* lwp = &labw[w * 1024];

        unsigned pkbuf[16];

        #pragma unroll 1
        for (int b = 0; b < 4; ++b) {
            float4 cv[4]; unsigned cl[4];
            #pragma unroll
            for (int j = 0; j < 4; ++j) {
                cv[j] = src[(b * 4 + j) * 64 + l];
                cl[j] = lwp[(b * 4 + j) * 64 + l];
            }
            #pragma unroll
            for (int j = 0; j < 4; ++j) {
                const unsigned lw = cl[j];
                const float4 v = cv[j];
                br[lw & 31] += v.x;
                br[(lw >> 8) & 31] += v.y;
                br[(lw >> 16) & 31] += v.z;
                br[(lw >> 24) & 31] += v.w;
                int pk = 0;
                pk = __builtin_amdgcn_cvt_pk_fp8_f32(v.x, v.y, pk, false);
                pk = __builtin_amdgcn_cvt_pk_fp8_f32(v.z, v.w, pk, true);
                pkbuf[b * 4 + j] = (unsigned)pk;
            }
        }

        // write burst (fire-and-forget NT stores)
        #pragma unroll
        for (int i = 0; i < 16; ++i)
            __builtin_nontemporal_store(pkbuf[i], &dst8[i * 64 + l]);

        // wave-local flush: lane k sums this wave's 64 rows at column k.
        // In-order per-wave LDS pipe + may-alias ordering make this safe without
        // a block barrier; wave_barrier() fences compiler scheduling.
        __builtin_amdgcn_wave_barrier();
        if (l < KCLS) {
            float s = 0.0f;
            const int rbase = w * 64;
            #pragma unroll 8
            for (int r = 0; r < 64; ++r) s += bins[(rbase + r) * 21 + l];
            unsafeAtomicAdd(&ws[WS_SUMS + l * CCH + c], s);
        }
        __builtin_amdgcn_wave_barrier();
        if (c4 < CPG - 1) {
            #pragma unroll
            for (int k = 0; k < KCLS; ++k) br[k] = 0.0f;
        }
    }
}

// ---------------- K3: pull term from fp8 plane copy; 8-deep channel prefetch ----------------
// grid: 1024 chunks of 1024 pixels, block 256 (4 px/thread), reversed order.
__global__ __launch_bounds__(256) void k3_var(const unsigned* __restrict__ fp8buf,
                                              const int* __restrict__ tgt,
                                              float* __restrict__ ws) {
    const int t = threadIdx.x;
    const int cid = 1023 - blockIdx.x;
    const int n = cid >> 8;
    const int hwb = (cid & 255) * 1024;

    __shared__ float ct[CCH * 20];       // ct[c*20 + k]
    __shared__ float cntS[KCLS];
    __shared__ float varh[80];

    if (t < KCLS) cntS[t] = ws[WS_COUNTS + t];
    if (t < 80) varh[t] = 0.0f;
    __syncthreads();
    for (int i = t; i < CCH * 20; i += 256) {
        int c = i / 20, k = i % 20;
        ct[i] = (k < KCLS) ? ws[WS_SUMS + k * CCH + c] / fmaxf(cntS[k], 1.0f) : 0.0f;
    }

    const int4 l0 = ((const int4*)(tgt + n * HW + hwb))[t];
    const int lab0 = l0.x, lab1 = l0.y, lab2 = l0.z, lab3 = l0.w;
    float a0 = 0.0f, a1 = 0.0f, a2 = 0.0f, a3 = 0.0f;
    __syncthreads();

    const unsigned* base8 = fp8buf + (((size_t)n * CCH * HW + hwb) >> 2);

    unsigned wb[8], nb[8];
    #pragma unroll
    for (int j = 0; j < 8; ++j) wb[j] = base8[j * (HW / 4) + t];

    #pragma unroll 1
    for (int cb = 0; cb < 8; ++cb) {
        if (cb < 7) {
            #pragma unroll
            for (int j = 0; j < 8; ++j) nb[j] = base8[((cb + 1) * 8 + j) * (HW / 4) + t];
        }
        const int cbase = cb * 8;
        #pragma unroll
        for (int j = 0; j < 8; ++j) {
            const unsigned w8 = wb[j];
            f32x2 lo = __builtin_amdgcn_cvt_pk_f32_fp8(w8, false);
            f32x2 hi = __builtin_amdgcn_cvt_pk_f32_fp8(w8, true);
            const float* row = &ct[(cbase + j) * 20];
            float m0 = row[lab0], m1 = row[lab1], m2 = row[lab2], m3 = row[lab3];
            float d0 = lo.x - m0, d1 = lo.y - m1, d2 = hi.x - m2, d3 = hi.y - m3;
            a0 = fmaf(d0, d0, a0);
            a1 = fmaf(d1, d1, a1);
            a2 = fmaf(d2, d2, a2);
            a3 = fmaf(d3, d3, a3);
        }
        #pragma unroll
        for (int j = 0; j < 8; ++j) wb[j] = nb[j];
    }

    const int rep = (t & 3) * KCLS;
    {
        float d, r;
        d = sqrtf(fmaxf(a0, 1e-12f)); r = d - 0.5f; if (r > 0.0f) ldsAdd(&varh[rep + lab0], r * r);
        d = sqrtf(fmaxf(a1, 1e-12f)); r = d - 0.5f; if (r > 0.0f) ldsAdd(&varh[rep + lab1], r * r);
        d = sqrtf(fmaxf(a2, 1e-12f)); r = d - 0.5f; if (r > 0.0f) ldsAdd(&varh[rep + lab2], r * r);
        d = sqrtf(fmaxf(a3, 1e-12f)); r = d - 0.5f; if (r > 0.0f) ldsAdd(&varh[rep + lab3], r * r);
    }
    __syncthreads();
    if (t < KCLS) {
        float s = varh[t] + varh[19 + t] + varh[38 + t] + varh[57 + t];
        unsafeAtomicAdd(&ws[WS_VARSUM + t], s);
    }
}

// ---------------- K4: centers + push + reg + final combine (1 block) ----------------
__global__ __launch_bounds__(256) void k4_final(const float* __restrict__ ws,
                                                float* __restrict__ out) {
    __shared__ float ct[CCH * 20];
    __shared__ float cntS[KCLS];
    __shared__ float acc[2];
    const int t = threadIdx.x;
    if (t < KCLS) cntS[t] = ws[WS_COUNTS + t];
    if (t < 2) acc[t] = 0.0f;
    __syncthreads();
    for (int i = t; i < CCH * 20; i += 256) {
        int c = i / 20, k = i % 20;
        ct[i] = (k < KCLS) ? ws[WS_SUMS + k * CCH + c] / fmaxf(cntS[k], 1.0f) : 0.0f;
    }
    __syncthreads();

    for (int p = t; p < KCLS * KCLS; p += 256) {
        int i = p / KCLS, j = p % KCLS;
        if (i != j && cntS[i] > 20.0f && cntS[j] > 20.0f) {
            float sq = 0.0f;
            #pragma unroll 8
            for (int c = 0; c < CCH; ++c) {
                float d = ct[c * 20 + i] - ct[c * 20 + j];
                sq = fmaf(d, d, sq);
            }
            float pd = sqrtf(sq);
            float r = 3.0f - pd;        // 2*DELTA - pd
            if (r > 0.0f) atomicAdd(&acc[0], r * r);
        }
    }
    if (t < KCLS && cntS[t] > 20.0f) {
        float sq = 0.0f;
        #pragma unroll 8
        for (int c = 0; c < CCH; ++c) { float v = ct[c * 20 + t]; sq = fmaf(v, v, sq); }
        atomicAdd(&acc[1], sqrtf(sq));
    }
    __syncthreads();

    if (t < 64) {
        float v = 0.0f;
        if (t < KCLS) {
            float c = cntS[t];
            if (c > 20.0f) v = ws[WS_VARSUM + t] / fmaxf(c, 1.0f);
        }
        #pragma unroll
        for (int s = 32; s > 0; s >>= 1) v += __shfl_down(v, s);
        if (t == 0) {
            float nv = 0.0f;
            for (int k = 0; k < KCLS; ++k) nv += (cntS[k] > 20.0f) ? 1.0f : 0.0f;
            float loss_dis = acc[0] / fmaxf(nv * (nv - 1.0f), 1.0f);
            float loss_reg = acc[1] / fmaxf(nv, 1.0f);
            out[0] = v / fmaxf(nv, 1.0f) + loss_dis + 0.001f * loss_reg;
        }
    }
}

extern "C" void kernel_launch(void* const* d_in, const int* in_sizes, int n_in,
                              void* d_out, int out_size, void* d_ws, size_t ws_size,
                              hipStream_t stream) {
    const float* pred = (const float*)d_in[0];
    const int* tgt = (const int*)d_in[1];
    float* ws = (float*)d_ws;
    unsigned* u8buf = (unsigned*)((char*)d_ws + WS_U8_BYTE_OFF);
    unsigned* fp8buf = (unsigned*)((char*)d_ws + WS_FP8_BYTE_OFF);
    float* out = (float*)d_out;

    hipLaunchKernelGGL(k0_prep, dim3(256), dim3(256), 0, stream, tgt, ws, u8buf);
    hipLaunchKernelGGL(k1_sums, dim3(NCHUNK, NCGRP), dim3(256), 0, stream, pred, u8buf, ws, fp8buf);
    hipLaunchKernelGGL(k3_var, dim3(1024), dim3(256), 0, stream, fp8buf, tgt, ws);
    hipLaunchKernelGGL(k4_final, dim3(1), dim3(256), 0, stream, ws, out);
}

// Round 21
// 124.915 us; speedup vs baseline: 1.4399x; 1.4399x over previous
//
#include <hip/hip_runtime.h>

#define KCLS 19
#define CCH 64
#define HW (512*512)
#define NPIX (4*HW)          // 1,048,576 pixels

// K1 geometry: channel-major contiguous
#define CHUNK 16384          // pixels per chunk (16 chunks per image)
#define NCHUNK (NPIX/CHUNK)  // 64
#define NCGRP 16             // channel groups of 4
#define CPG 4

// ws float offsets (stats area)
#define WS_COUNTS  0      // 19
#define WS_SUMS    32     // [k*64+c], 1216
#define WS_VARSUM  1280   // 19
#define WS_NFLOATS 2576
#define WS_U8_BYTE_OFF  16384                      // packed u8 labels, 1 MB
#define WS_FP8_BYTE_OFF (16384 + 1048576)          // fp8 copy of pred (plane layout), 64 MB

typedef float f32x2 __attribute__((ext_vector_type(2)));

__device__ __forceinline__ void ldsAdd(float* p, float v) { unsafeAtomicAdd(p, v); }

// ---------------- K0: zero stats + pack labels to u8 ----------------
__global__ __launch_bounds__(256) void k0_prep(const int* __restrict__ tgt,
                                               float* __restrict__ ws,
                                               unsigned* __restrict__ u8buf) {
    const int j = blockIdx.x * 256 + threadIdx.x;
    if (blockIdx.x == 0) {
        for (int i = threadIdx.x; i < WS_NFLOATS; i += 256) ws[i] = 0.0f;
    }
    const int4* tg4 = (const int4*)tgt;
    unsigned pk[4];
    #pragma unroll
    for (int q = 0; q < 4; ++q) {
        int4 L = tg4[j * 4 + q];
        pk[q] = (unsigned)(L.x & 0xFF) | ((unsigned)(L.y & 0xFF) << 8) |
                ((unsigned)(L.z & 0xFF) << 16) | ((unsigned)(L.w & 0xFF) << 24);
    }
    uint4 o; o.x = pk[0]; o.y = pk[1]; o.z = pk[2]; o.w = pk[3];
    ((uint4*)u8buf)[j] = o;
}

// ---------------- K1: counts + sums + fp8 copy; stores BATCHED per channel (NT) ----------------
// grid (64 chunks, 16 cgroups), block 256 (4 waves).
// Read phase (64 KB/wave-channel) and write phase (16 KB burst) separated.
// Block-level flush with per-channel barriers (R19-proven; barrier-free variant
// regressed via LDS bank conflicts, R20).
__global__ __launch_bounds__(256) void k1_sums(const float* __restrict__ pred,
                                               const unsigned* __restrict__ u8buf,
                                               float* __restrict__ ws,
                                               unsigned* __restrict__ fp8buf) {
    const int t = threadIdx.x;
    const int l = t & 63;
    const int w = t >> 6;
    const int chunk = blockIdx.x;        // 64
    const int cg = blockIdx.y;           // 16
    const int n = chunk >> 4;
    const int choff = (chunk & 15) * CHUNK;

    __shared__ unsigned labw[CHUNK / 4];      // 16 KB packed u8 labels
    __shared__ float bins[256 * 21];          // 21.5 KB thread-private rows
    __shared__ float cnt[16 * 21];            // 1.3 KB replica count hist
    __shared__ float red[4 * 21];             // flush partials

    float* br = &bins[t * 21];
    #pragma unroll
    for (int k = 0; k < KCLS; ++k) br[k] = 0.0f;
    for (int i = t; i < 16 * 21; i += 256) cnt[i] = 0.0f;
    __syncthreads();

    {
        const uint4* g4 = (const uint4*)(u8buf + chunk * (CHUNK / 4));
        #pragma unroll
        for (int q = 0; q < 4; ++q) {
            uint4 v = g4[t + q * 256];
            ((uint4*)labw)[t + q * 256] = v;
        }
        unsigned cw = ((const unsigned*)(u8buf + chunk * (CHUNK / 4)))[cg * 256 + t];
        float* cr = &cnt[(t & 15) * 21];
        ldsAdd(&cr[cw & 31], 1.0f);
        ldsAdd(&cr[(cw >> 8) & 31], 1.0f);
        ldsAdd(&cr[(cw >> 16) & 31], 1.0f);
        ldsAdd(&cr[(cw >> 24) & 31], 1.0f);
    }
    __syncthreads();

    for (int c4 = 0; c4 < CPG; ++c4) {
        const int c = cg * CPG + c4;
        const size_t plane = (size_t)(n * CCH + c) * HW + choff;
        const float4* src = (const float4*)(pred + plane) + w * 1024;
        unsigned* dst8 = fp8buf + (plane >> 2) + w * 1024;
        const unsigned* lwp = &labw[w * 1024];

        unsigned pkbuf[16];                   // fp8 words buffered in VGPRs

        #pragma unroll 1
        for (int b = 0; b < 4; ++b) {
            float4 cv[4]; unsigned cl[4];
            #pragma unroll
            for (int j = 0; j < 4; ++j) {
                cv[j] = src[(b * 4 + j) * 64 + l];
                cl[j] = lwp[(b * 4 + j) * 64 + l];
            }
            #pragma unroll
            for (int j = 0; j < 4; ++j) {
                const unsigned lw = cl[j];
                const float4 v = cv[j];
                br[lw & 31] += v.x;
                br[(lw >> 8) & 31] += v.y;
                br[(lw >> 16) & 31] += v.z;
                br[(lw >> 24) & 31] += v.w;
                int pk = 0;
                pk = __builtin_amdgcn_cvt_pk_fp8_f32(v.x, v.y, pk, false);
                pk = __builtin_amdgcn_cvt_pk_fp8_f32(v.z, v.w, pk, true);
                pkbuf[b * 4 + j] = (unsigned)pk;
            }
        }

        // write phase: 16 NT stores back-to-back (wave instr i = 256 B contiguous)
        #pragma unroll
        for (int i = 0; i < 16; ++i)
            __builtin_nontemporal_store(pkbuf[i], &dst8[i * 64 + l]);

        // flush channel c
        __syncthreads();
        if (l < KCLS) {
            float s = 0.0f;
            const int rbase = w * 64;
            #pragma unroll 8
            for (int r = 0; r < 64; ++r) s += bins[(rbase + r) * 21 + l];
            red[w * 21 + l] = s;
        }
        __syncthreads();
        if (t < KCLS) {
            float s = red[t] + red[21 + t] + red[42 + t] + red[63 + t];
            unsafeAtomicAdd(&ws[WS_SUMS + t * CCH + c], s);
        }
        #pragma unroll
        for (int k = 0; k < KCLS; ++k) br[k] = 0.0f;
        __syncthreads();
    }

    if (t < KCLS) {
        float s = 0.0f;
        #pragma unroll
        for (int r = 0; r < 16; ++r) s += cnt[r * 21 + t];
        unsafeAtomicAdd(&ws[WS_COUNTS + t], s);
    }
}

// ---------------- K3: pull term from fp8 plane copy; 8-deep channel prefetch ----------------
// grid: 1024 chunks of 1024 pixels, block 256 (4 px/thread), reversed order.
__global__ __launch_bounds__(256) void k3_var(const unsigned* __restrict__ fp8buf,
                                              const int* __restrict__ tgt,
                                              float* __restrict__ ws) {
    const int t = threadIdx.x;
    const int cid = 1023 - blockIdx.x;
    const int n = cid >> 8;
    const int hwb = (cid & 255) * 1024;

    __shared__ float ct[CCH * 20];       // ct[c*20 + k]
    __shared__ float cntS[KCLS];
    __shared__ float varh[80];

    if (t < KCLS) cntS[t] = ws[WS_COUNTS + t];
    if (t < 80) varh[t] = 0.0f;
    __syncthreads();
    for (int i = t; i < CCH * 20; i += 256) {
        int c = i / 20, k = i % 20;
        ct[i] = (k < KCLS) ? ws[WS_SUMS + k * CCH + c] / fmaxf(cntS[k], 1.0f) : 0.0f;
    }

    const int4 l0 = ((const int4*)(tgt + n * HW + hwb))[t];
    const int lab0 = l0.x, lab1 = l0.y, lab2 = l0.z, lab3 = l0.w;
    float a0 = 0.0f, a1 = 0.0f, a2 = 0.0f, a3 = 0.0f;
    __syncthreads();

    const unsigned* base8 = fp8buf + (((size_t)n * CCH * HW + hwb) >> 2);

    unsigned wb[8], nb[8];
    #pragma unroll
    for (int j = 0; j < 8; ++j) wb[j] = base8[j * (HW / 4) + t];

    #pragma unroll 1
    for (int cb = 0; cb < 8; ++cb) {
        if (cb < 7) {
            #pragma unroll
            for (int j = 0; j < 8; ++j) nb[j] = base8[((cb + 1) * 8 + j) * (HW / 4) + t];
        }
        const int cbase = cb * 8;
        #pragma unroll
        for (int j = 0; j < 8; ++j) {
            const unsigned w8 = wb[j];
            f32x2 lo = __builtin_amdgcn_cvt_pk_f32_fp8(w8, false);
            f32x2 hi = __builtin_amdgcn_cvt_pk_f32_fp8(w8, true);
            const float* row = &ct[(cbase + j) * 20];
            float m0 = row[lab0], m1 = row[lab1], m2 = row[lab2], m3 = row[lab3];
            float d0 = lo.x - m0, d1 = lo.y - m1, d2 = hi.x - m2, d3 = hi.y - m3;
            a0 = fmaf(d0, d0, a0);
            a1 = fmaf(d1, d1, a1);
            a2 = fmaf(d2, d2, a2);
            a3 = fmaf(d3, d3, a3);
        }
        #pragma unroll
        for (int j = 0; j < 8; ++j) wb[j] = nb[j];
    }

    const int rep = (t & 3) * KCLS;
    {
        float d, r;
        d = sqrtf(fmaxf(a0, 1e-12f)); r = d - 0.5f; if (r > 0.0f) ldsAdd(&varh[rep + lab0], r * r);
        d = sqrtf(fmaxf(a1, 1e-12f)); r = d - 0.5f; if (r > 0.0f) ldsAdd(&varh[rep + lab1], r * r);
        d = sqrtf(fmaxf(a2, 1e-12f)); r = d - 0.5f; if (r > 0.0f) ldsAdd(&varh[rep + lab2], r * r);
        d = sqrtf(fmaxf(a3, 1e-12f)); r = d - 0.5f; if (r > 0.0f) ldsAdd(&varh[rep + lab3], r * r);
    }
    __syncthreads();
    if (t < KCLS) {
        float s = varh[t] + varh[19 + t] + varh[38 + t] + varh[57 + t];
        unsafeAtomicAdd(&ws[WS_VARSUM + t], s);
    }
}

// ---------------- K4: centers + push + reg + final combine (1 block) ----------------
__global__ __launch_bounds__(256) void k4_final(const float* __restrict__ ws,
                                                float* __restrict__ out) {
    __shared__ float ct[CCH * 20];
    __shared__ float cntS[KCLS];
    __shared__ float acc[2];
    const int t = threadIdx.x;
    if (t < KCLS) cntS[t] = ws[WS_COUNTS + t];
    if (t < 2) acc[t] = 0.0f;
    __syncthreads();
    for (int i = t; i < CCH * 20; i += 256) {
        int c = i / 20, k = i % 20;
        ct[i] = (k < KCLS) ? ws[WS_SUMS + k * CCH + c] / fmaxf(cntS[k], 1.0f) : 0.0f;
    }
    __syncthreads();

    for (int p = t; p < KCLS * KCLS; p += 256) {
        int i = p / KCLS, j = p % KCLS;
        if (i != j && cntS[i] > 20.0f && cntS[j] > 20.0f) {
            float sq = 0.0f;
            #pragma unroll 8
            for (int c = 0; c < CCH; ++c) {
                float d = ct[c * 20 + i] - ct[c * 20 + j];
                sq = fmaf(d, d, sq);
            }
            float pd = sqrtf(sq);
            float r = 3.0f - pd;        // 2*DELTA - pd
            if (r > 0.0f) atomicAdd(&acc[0], r * r);
        }
    }
    if (t < KCLS && cntS[t] > 20.0f) {
        float sq = 0.0f;
        #pragma unroll 8
        for (int c = 0; c < CCH; ++c) { float v = ct[c * 20 + t]; sq = fmaf(v, v, sq); }
        atomicAdd(&acc[1], sqrtf(sq));
    }
    __syncthreads();

    if (t < 64) {
        float v = 0.0f;
        if (t < KCLS) {
            float c = cntS[t];
            if (c > 20.0f) v = ws[WS_VARSUM + t] / fmaxf(c, 1.0f);
        }
        #pragma unroll
        for (int s = 32; s > 0; s >>= 1) v += __shfl_down(v, s);
        if (t == 0) {
            float nv = 0.0f;
            for (int k = 0; k < KCLS; ++k) nv += (cntS[k] > 20.0f) ? 1.0f : 0.0f;
            float loss_dis = acc[0] / fmaxf(nv * (nv - 1.0f), 1.0f);
            float loss_reg = acc[1] / fmaxf(nv, 1.0f);
            out[0] = v / fmaxf(nv, 1.0f) + loss_dis + 0.001f * loss_reg;
        }
    }
}

extern "C" void kernel_launch(void* const* d_in, const int* in_sizes, int n_in,
                              void* d_out, int out_size, void* d_ws, size_t ws_size,
                              hipStream_t stream) {
    const float* pred = (const float*)d_in[0];
    const int* tgt = (const int*)d_in[1];
    float* ws = (float*)d_ws;
    unsigned* u8buf = (unsigned*)((char*)d_ws + WS_U8_BYTE_OFF);
    unsigned* fp8buf = (unsigned*)((char*)d_ws + WS_FP8_BYTE_OFF);
    float* out = (float*)d_out;

    hipLaunchKernelGGL(k0_prep, dim3(256), dim3(256), 0, stream, tgt, ws, u8buf);
    hipLaunchKernelGGL(k1_sums, dim3(NCHUNK, NCGRP), dim3(256), 0, stream, pred, u8buf, ws, fp8buf);
    hipLaunchKernelGGL(k3_var, dim3(1024), dim3(256), 0, stream, fp8buf, tgt, ws);
    hipLaunchKernelGGL(k4_final, dim3(1), dim3(256), 0, stream, ws, out);
}

// Round 22
// 114.686 us; speedup vs baseline: 1.5684x; 1.0892x over previous
//
#include <hip/hip_runtime.h>

#define KCLS 19
#define CCH 64
#define HW (512*512)
#define NPIX (4*HW)          // 1,048,576 pixels

#define CHUNK 16384          // pixels per chunk (16 chunks per image)
#define NCHUNK (NPIX/CHUNK)  // 64

// ws float offsets (stats area)
#define WS_COUNTS  0      // 19
#define WS_SUMS    32     // [k*64+c], 1216
#define WS_VARSUM  1280   // 19
#define WS_NFLOATS 2576
#define WS_CNTP    2624   // 256 x 19 per-block count partials (plain stores)
#define WS_U8_BYTE_OFF  65536                      // packed u8 labels, 1 MB
#define WS_FP8_BYTE_OFF (65536 + 1048576)          // fp8 copy of pred (plane layout), 64 MB

typedef float f32x2 __attribute__((ext_vector_type(2)));

__device__ __forceinline__ void ldsAdd(float* p, float v) { unsafeAtomicAdd(p, v); }

// ---------------- K0: zero stats + pack labels + per-block count partials ----------------
// 256 blocks x 256 thr; thread j packs 16 labels; per-thread LDS rows for counts.
__global__ __launch_bounds__(256) void k0_prep(const int* __restrict__ tgt,
                                               float* __restrict__ ws,
                                               unsigned* __restrict__ u8buf) {
    const int t = threadIdx.x;
    const int l = t & 63;
    const int w = t >> 6;
    const int j = blockIdx.x * 256 + t;

    __shared__ float bins[256 * 21];
    __shared__ float red[4 * 21];

    float* br = &bins[t * 21];
    #pragma unroll
    for (int k = 0; k < KCLS; ++k) br[k] = 0.0f;
    if (blockIdx.x == 0) {
        for (int i = t; i < WS_NFLOATS; i += 256) ws[i] = 0.0f;
    }

    const int4* tg4 = (const int4*)tgt;
    unsigned pk[4];
    #pragma unroll
    for (int q = 0; q < 4; ++q) {
        int4 L = tg4[j * 4 + q];
        pk[q] = (unsigned)(L.x & 0xFF) | ((unsigned)(L.y & 0xFF) << 8) |
                ((unsigned)(L.z & 0xFF) << 16) | ((unsigned)(L.w & 0xFF) << 24);
        br[L.x & 31] += 1.0f;
        br[L.y & 31] += 1.0f;
        br[L.z & 31] += 1.0f;
        br[L.w & 31] += 1.0f;
    }
    uint4 o; o.x = pk[0]; o.y = pk[1]; o.z = pk[2]; o.w = pk[3];
    ((uint4*)u8buf)[j] = o;

    __syncthreads();
    if (l < KCLS) {
        float s = 0.0f;
        const int rbase = w * 64;
        #pragma unroll 8
        for (int r = 0; r < 64; ++r) s += bins[(rbase + r) * 21 + l];
        red[w * 21 + l] = s;
    }
    __syncthreads();
    if (t < KCLS) {
        float s = red[t] + red[21 + t] + red[42 + t] + red[63 + t];
        ws[WS_CNTP + blockIdx.x * 19 + t] = s;    // plain store (area never zeroed/read stale)
    }
}

// ---------------- K1: one channel per block; zero mid-kernel barriers ----------------
// grid (64 chunks, 64 channels), block 256 (4 waves). Each thread: 16 float4 iters.
// Labels direct from u8buf (L2-hot). Single flush barrier at end -> one store-drain.
__global__ __launch_bounds__(256) void k1_sums(const float* __restrict__ pred,
                                               const unsigned* __restrict__ u8buf,
                                               float* __restrict__ ws,
                                               unsigned* __restrict__ fp8buf) {
    const int t = threadIdx.x;
    const int l = t & 63;
    const int w = t >> 6;
    const int chunk = blockIdx.x;        // 64
    const int c = blockIdx.y;            // 64
    const int n = chunk >> 4;
    const int choff = (chunk & 15) * CHUNK;

    __shared__ float bins[256 * 21];     // thread-private rows
    __shared__ float red[4 * 21];

    float* br = &bins[t * 21];
    #pragma unroll
    for (int k = 0; k < KCLS; ++k) br[k] = 0.0f;

    // c==0 blocks fold count partials into WS_COUNTS (k0 done at kernel boundary)
    if (c == 0 && t < 76) {
        float v = ws[WS_CNTP + (chunk * 4 + t / 19) * 19 + (t % 19)];
        unsafeAtomicAdd(&ws[WS_COUNTS + (t % 19)], v);
    }

    const size_t plane = (size_t)(n * CCH + c) * HW + choff;
    const float4* src = (const float4*)(pred + plane) + w * 1024;
    unsigned* dst8 = fp8buf + (plane >> 2) + w * 1024;
    const unsigned* lwp = u8buf + chunk * 4096 + w * 1024;

    unsigned pkbuf[16];

    #pragma unroll 1
    for (int b = 0; b < 4; ++b) {
        float4 cv[4]; unsigned cl[4];
        #pragma unroll
        for (int j = 0; j < 4; ++j) {
            cv[j] = src[(b * 4 + j) * 64 + l];
            cl[j] = lwp[(b * 4 + j) * 64 + l];
        }
        #pragma unroll
        for (int j = 0; j < 4; ++j) {
            const unsigned lw = cl[j];
            const float4 v = cv[j];
            br[lw & 31] += v.x;
            br[(lw >> 8) & 31] += v.y;
            br[(lw >> 16) & 31] += v.z;
            br[(lw >> 24) & 31] += v.w;
            int pk = 0;
            pk = __builtin_amdgcn_cvt_pk_fp8_f32(v.x, v.y, pk, false);
            pk = __builtin_amdgcn_cvt_pk_fp8_f32(v.z, v.w, pk, true);
            pkbuf[b * 4 + j] = (unsigned)pk;
        }
    }

    // NT store burst (drained only once, at the flush barrier below)
    #pragma unroll
    for (int i = 0; i < 16; ++i)
        __builtin_nontemporal_store(pkbuf[i], &dst8[i * 64 + l]);

    // single flush
    __syncthreads();
    if (l < KCLS) {
        float s = 0.0f;
        const int rbase = w * 64;
        #pragma unroll 8
        for (int r = 0; r < 64; ++r) s += bins[(rbase + r) * 21 + l];
        red[w * 21 + l] = s;
    }
    __syncthreads();
    if (t < KCLS) {
        float s = red[t] + red[21 + t] + red[42 + t] + red[63 + t];
        unsafeAtomicAdd(&ws[WS_SUMS + t * CCH + c], s);
    }
}

// ---------------- K3: pull term from fp8 plane copy; 8-deep channel prefetch ----------------
// grid: 1024 chunks of 1024 pixels, block 256 (4 px/thread), reversed order.
__global__ __launch_bounds__(256) void k3_var(const unsigned* __restrict__ fp8buf,
                                              const int* __restrict__ tgt,
                                              float* __restrict__ ws) {
    const int t = threadIdx.x;
    const int cid = 1023 - blockIdx.x;
    const int n = cid >> 8;
    const int hwb = (cid & 255) * 1024;

    __shared__ float ct[CCH * 20];       // ct[c*20 + k]
    __shared__ float cntS[KCLS];
    __shared__ float varh[80];

    if (t < KCLS) cntS[t] = ws[WS_COUNTS + t];
    if (t < 80) varh[t] = 0.0f;
    __syncthreads();
    for (int i = t; i < CCH * 20; i += 256) {
        int c = i / 20, k = i % 20;
        ct[i] = (k < KCLS) ? ws[WS_SUMS + k * CCH + c] / fmaxf(cntS[k], 1.0f) : 0.0f;
    }

    const int4 l0 = ((const int4*)(tgt + n * HW + hwb))[t];
    const int lab0 = l0.x, lab1 = l0.y, lab2 = l0.z, lab3 = l0.w;
    float a0 = 0.0f, a1 = 0.0f, a2 = 0.0f, a3 = 0.0f;
    __syncthreads();

    const unsigned* base8 = fp8buf + (((size_t)n * CCH * HW + hwb) >> 2);

    unsigned wb[8], nb[8];
    #pragma unroll
    for (int j = 0; j < 8; ++j) wb[j] = base8[j * (HW / 4) + t];

    #pragma unroll 1
    for (int cb = 0; cb < 8; ++cb) {
        if (cb < 7) {
            #pragma unroll
            for (int j = 0; j < 8; ++j) nb[j] = base8[((cb + 1) * 8 + j) * (HW / 4) + t];
        }
        const int cbase = cb * 8;
        #pragma unroll
        for (int j = 0; j < 8; ++j) {
            const unsigned w8 = wb[j];
            f32x2 lo = __builtin_amdgcn_cvt_pk_f32_fp8(w8, false);
            f32x2 hi = __builtin_amdgcn_cvt_pk_f32_fp8(w8, true);
            const float* row = &ct[(cbase + j) * 20];
            float m0 = row[lab0], m1 = row[lab1], m2 = row[lab2], m3 = row[lab3];
            float d0 = lo.x - m0, d1 = lo.y - m1, d2 = hi.x - m2, d3 = hi.y - m3;
            a0 = fmaf(d0, d0, a0);
            a1 = fmaf(d1, d1, a1);
            a2 = fmaf(d2, d2, a2);
            a3 = fmaf(d3, d3, a3);
        }
        #pragma unroll
        for (int j = 0; j < 8; ++j) wb[j] = nb[j];
    }

    const int rep = (t & 3) * KCLS;
    {
        float d, r;
        d = sqrtf(fmaxf(a0, 1e-12f)); r = d - 0.5f; if (r > 0.0f) ldsAdd(&varh[rep + lab0], r * r);
        d = sqrtf(fmaxf(a1, 1e-12f)); r = d - 0.5f; if (r > 0.0f) ldsAdd(&varh[rep + lab1], r * r);
        d = sqrtf(fmaxf(a2, 1e-12f)); r = d - 0.5f; if (r > 0.0f) ldsAdd(&varh[rep + lab2], r * r);
        d = sqrtf(fmaxf(a3, 1e-12f)); r = d - 0.5f; if (r > 0.0f) ldsAdd(&varh[rep + lab3], r * r);
    }
    __syncthreads();
    if (t < KCLS) {
        float s = varh[t] + varh[19 + t] + varh[38 + t] + varh[57 + t];
        unsafeAtomicAdd(&ws[WS_VARSUM + t], s);
    }
}

// ---------------- K4: centers + push + reg + final combine (1 block) ----------------
__global__ __launch_bounds__(256) void k4_final(const float* __restrict__ ws,
                                                float* __restrict__ out) {
    __shared__ float ct[CCH * 20];
    __shared__ float cntS[KCLS];
    __shared__ float acc[2];
    const int t = threadIdx.x;
    if (t < KCLS) cntS[t] = ws[WS_COUNTS + t];
    if (t < 2) acc[t] = 0.0f;
    __syncthreads();
    for (int i = t; i < CCH * 20; i += 256) {
        int c = i / 20, k = i % 20;
        ct[i] = (k < KCLS) ? ws[WS_SUMS + k * CCH + c] / fmaxf(cntS[k], 1.0f) : 0.0f;
    }
    __syncthreads();

    for (int p = t; p < KCLS * KCLS; p += 256) {
        int i = p / KCLS, j = p % KCLS;
        if (i != j && cntS[i] > 20.0f && cntS[j] > 20.0f) {
            float sq = 0.0f;
            #pragma unroll 8
            for (int c = 0; c < CCH; ++c) {
                float d = ct[c * 20 + i] - ct[c * 20 + j];
                sq = fmaf(d, d, sq);
            }
            float pd = sqrtf(sq);
            float r = 3.0f - pd;        // 2*DELTA - pd
            if (r > 0.0f) atomicAdd(&acc[0], r * r);
        }
    }
    if (t < KCLS && cntS[t] > 20.0f) {
        float sq = 0.0f;
        #pragma unroll 8
        for (int c = 0; c < CCH; ++c) { float v = ct[c * 20 + t]; sq = fmaf(v, v, sq); }
        atomicAdd(&acc[1], sqrtf(sq));
    }
    __syncthreads();

    if (t < 64) {
        float v = 0.0f;
        if (t < KCLS) {
            float c = cntS[t];
            if (c > 20.0f) v = ws[WS_VARSUM + t] / fmaxf(c, 1.0f);
        }
        #pragma unroll
        for (int s = 32; s > 0; s >>= 1) v += __shfl_down(v, s);
        if (t == 0) {
            float nv = 0.0f;
            for (int k = 0; k < KCLS; ++k) nv += (cntS[k] > 20.0f) ? 1.0f : 0.0f;
            float loss_dis = acc[0] / fmaxf(nv * (nv - 1.0f), 1.0f);
            float loss_reg = acc[1] / fmaxf(nv, 1.0f);
            out[0] = v / fmaxf(nv, 1.0f) + loss_dis + 0.001f * loss_reg;
        }
    }
}

extern "C" void kernel_launch(void* const* d_in, const int* in_sizes, int n_in,
                              void* d_out, int out_size, void* d_ws, size_t ws_size,
                              hipStream_t stream) {
    const float* pred = (const float*)d_in[0];
    const int* tgt = (const int*)d_in[1];
    float* ws = (float*)d_ws;
    unsigned* u8buf = (unsigned*)((char*)d_ws + WS_U8_BYTE_OFF);
    unsigned* fp8buf = (unsigned*)((char*)d_ws + WS_FP8_BYTE_OFF);
    float* out = (float*)d_out;

    hipLaunchKernelGGL(k0_prep, dim3(256), dim3(256), 0, stream, tgt, ws, u8buf);
    hipLaunchKernelGGL(k1_sums, dim3(NCHUNK, CCH), dim3(256), 0, stream, pred, u8buf, ws, fp8buf);
    hipLaunchKernelGGL(k3_var, dim3(1024), dim3(256), 0, stream, fp8buf, tgt, ws);
    hipLaunchKernelGGL(k4_final, dim3(1), dim3(256), 0, stream, ws, out);
}